// Round 6
// baseline (324.299 us; speedup 1.0000x reference)
//
#include <hip/hip_runtime.h>

#define EPS 1e-5f

typedef __attribute__((ext_vector_type(8))) short bf16x8;
typedef __attribute__((ext_vector_type(4))) short short4v;
typedef __attribute__((ext_vector_type(4))) float f32x4;

__device__ __forceinline__ float fexp(float x){ return __builtin_amdgcn_exp2f(x*1.4426950408889634f); }
__device__ __forceinline__ float frcp(float x){ return __builtin_amdgcn_rcpf(x); }
__device__ __forceinline__ float fsig(float x){ return frcp(1.0f + fexp(-x)); }
__device__ __forceinline__ float ftanh(float x){ return 1.0f - 2.0f*frcp(fexp(2.0f*x) + 1.0f); }

__device__ __forceinline__ short bfhi(float v){ return (short)(__float_as_uint(v) >> 16); }
__device__ __forceinline__ float bfhif(float v){ return __uint_as_float(__float_as_uint(v) & 0xFFFF0000u); }

// ws float layout:
//   [0]            mean_x
//   [16..1040)     mean partials
//   [1056..1312)   add0 ; [1312..1568) add1
// shorts region SB = (short*)(ws + 2048)  (only used when ws_size >= WS_NEED):
//   SB[0..16384)      wlo0 (MFMA A-fragment order, 2048 slots x 8 bf16)
//   SB[16384..32768)  wlo1
#define WS_NEED (2048*4 + 2*16384*2)   // 73728 bytes

// ---------------- mean(x) reduction (deterministic, 2-stage) ----------------
__global__ void mean_part(const float* __restrict__ x, int P, float* __restrict__ part)
{
    __shared__ float red[256];
    int tid = blockIdx.x*256 + threadIdx.x;
    float s = 0.0f;
    for (int i = tid; i < P; i += 256*1024) s += x[i];
    red[threadIdx.x] = s; __syncthreads();
    for (int w = 128; w > 0; w >>= 1){
        if (threadIdx.x < w) red[threadIdx.x] += red[threadIdx.x + w];
        __syncthreads();
    }
    if (threadIdx.x == 0) part[blockIdx.x] = red[0];
}

__global__ void mean_fin(const float* __restrict__ part, float* __restrict__ ws, int P)
{
    __shared__ float red[1024];
    int t = threadIdx.x;
    red[t] = part[t]; __syncthreads();
    for (int w = 512; w > 0; w >>= 1){
        if (t < w) red[t] += red[t + w];
        __syncthreads();
    }
    if (t == 0) ws[0] = red[0] / (float)P;
}

// ---------------- add-vector precompute: add = LN(bh,gh,bgh) + bgi ----------------
__global__ void precomp_add(
    const float* __restrict__ bh0, const float* __restrict__ gh0,
    const float* __restrict__ bgh0, const float* __restrict__ bgi0,
    const float* __restrict__ bh1, const float* __restrict__ gh1,
    const float* __restrict__ bgh1, const float* __restrict__ bgi1,
    float* __restrict__ ws)
{
    const int l = blockIdx.x;
    const float* bh  = l ? bh1  : bh0;
    const float* gh  = l ? gh1  : gh0;
    const float* bgh = l ? bgh1 : bgh0;
    const float* bgi = l ? bgi1 : bgi0;
    float* add = ws + 1056 + l*256;
    int t = threadIdx.x;

    __shared__ float r1[256], r2[256];
    float v = bh[t];
    r1[t] = v; r2[t] = v*v; __syncthreads();
    for (int w = 128; w > 0; w >>= 1){
        if (t < w){ r1[t] += r1[t+w]; r2[t] += r2[t+w]; }
        __syncthreads();
    }
    float m   = r1[0] * (1.0f/256.0f);
    float var = (r2[0] - 256.0f*m*m) * (1.0f/255.0f);
    float s   = sqrtf(fmaxf(var, 0.0f));
    float c   = (v - m) * frcp(s + EPS) * gh[t] + bgh[t];
    add[t] = c + bgi[t];
}

// ---------------- wlo fragment images (only when ws is big enough) ----------------
// 2048 slots per layer: slot = (mt*2+ks)*64 + lane ; lane holds 8 bf16-lo:
//   g = mt*16 + (lane&15), k = ks*32 + (lane>>4)*8 + j     (mt<16, ks<2)
__global__ void precomp_wlo(const float* __restrict__ Wi0, const float* __restrict__ Wi1,
                            float* __restrict__ ws)
{
    const int l = blockIdx.x;
    const float* Wi = l ? Wi1 : Wi0;
    short* wlos = (short*)(ws + 2048) + l*16384;
    int t = threadIdx.x;
    for (int i = 0; i < 8; ++i){               // 8*256 = 2048 slots (NOT 4096!)
        int slot = i*256 + t;                   // 0..2047
        int lane = slot & 63, mtks = slot >> 6; // mtks 0..31
        int mt = mtks >> 1, ks = mtks & 1;
        int g  = (mt << 4) + (lane & 15);
        int k  = (ks << 5) + ((lane >> 4) << 3);
        short tmp[8];
        #pragma unroll
        for (int j = 0; j < 8; ++j){
            float w = Wi[(g << 6) + k + j];
            tmp[j] = bfhi(w - bfhif(w));
        }
        short4v a = { tmp[0], tmp[1], tmp[2], tmp[3] };
        short4v b = { tmp[4], tmp[5], tmp[6], tmp[7] };
        *(short4v*)(wlos + slot*8)     = a;
        *(short4v*)(wlos + slot*8 + 4) = b;
    }
}

// ================= shared device helpers for both fwd variants =================
struct LayerParams { const float *bi, *gi, *addv, *gc, *bc; };

// ---------------- fast path: whi in LDS (32 KB), wlo streamed from global ----------------
__global__ __launch_bounds__(512, 4) void fwd_stream(
    const float* __restrict__ x,
    const float* __restrict__ W1, const float* __restrict__ b1,
    const float* __restrict__ g1, const float* __restrict__ be1,
    const float* __restrict__ Wi0, const float* __restrict__ bi0,
    const float* __restrict__ gi0, const float* __restrict__ gc0, const float* __restrict__ bc0,
    const float* __restrict__ Wi1, const float* __restrict__ bi1,
    const float* __restrict__ gi1, const float* __restrict__ gc1, const float* __restrict__ bc1,
    const float* __restrict__ Wo, const float* __restrict__ bo,
    const float* __restrict__ ws, float* __restrict__ out, int P)
{
    __shared__ short wl[16384];   // whi of current layer (32 KB)
    __shared__ short hb[16384];   // [wave][part][row16][cell64] swizzled (32 KB)

    const int tid  = threadIdx.x;
    const int wid  = tid >> 6;
    const int lane = tid & 63;
    const int c16  = lane & 15;
    const int q    = lane >> 4;
    const int row  = blockIdx.x*128 + wid*16 + c16;
    short* hbw = hb + wid*2048;
    const int swz = (c16 & 7) << 3;
    const short* SB = (const short*)(ws + 2048);

    auto stage_hi = [&](const float* __restrict__ W){
        #pragma unroll
        for (int i = 0; i < 8; ++i){
            int idx = i*512 + tid;                  // float4 chunk 0..4095
            int g = idx >> 4, k0 = (idx & 15) << 2;
            f32x4 w4 = *(const f32x4*)(W + (idx << 2));
            int si = ((g << 6) + k0) ^ ((g & 7) << 3);
            short4v hi = { bfhi(w4[0]), bfhi(w4[1]), bfhi(w4[2]), bfhi(w4[3]) };
            *(short4v*)(wl + si) = hi;
        }
    };

    stage_hi(Wi0);

    float xv = 0.0f;
    if (row < P) xv = x[row];
    else if (row == P) xv = ws[0];

    float h[16];
    {
        float sm = 0.f, sq = 0.f;
        #pragma unroll
        for (int mt4 = 0; mt4 < 4; ++mt4){
            const f32x4 w14 = *(const f32x4*)(W1 + mt4*16 + (q << 2));
            const f32x4 b14 = *(const f32x4*)(b1 + mt4*16 + (q << 2));
            #pragma unroll
            for (int r = 0; r < 4; ++r){
                float v = xv*w14[r] + b14[r];
                h[mt4*4+r] = v; sm += v; sq += v*v;
            }
        }
        sm += __shfl_xor(sm, 16); sm += __shfl_xor(sm, 32);
        sq += __shfl_xor(sq, 16); sq += __shfl_xor(sq, 32);
        const float m   = sm * (1.0f/64.0f);
        const float var = (sq - 64.0f*m*m) * (1.0f/63.0f);
        const float inv = frcp(sqrtf(fmaxf(var, 0.0f)) + EPS);
        #pragma unroll
        for (int mt4 = 0; mt4 < 4; ++mt4){
            const f32x4 g14  = *(const f32x4*)(g1  + mt4*16 + (q << 2));
            const f32x4 be14 = *(const f32x4*)(be1 + mt4*16 + (q << 2));
            #pragma unroll
            for (int r = 0; r < 4; ++r)
                h[mt4*4+r] = ftanh((h[mt4*4+r]-m)*inv*g14[r] + be14[r]);
        }
        #pragma unroll
        for (int mt4 = 0; mt4 < 4; ++mt4){
            int si = ((c16 << 6) + mt4*16 + (q << 2)) ^ swz;
            float a = h[mt4*4+0], b = h[mt4*4+1], c = h[mt4*4+2], d = h[mt4*4+3];
            short4v hi = { bfhi(a), bfhi(b), bfhi(c), bfhi(d) };
            short4v lo = { bfhi(a-bfhif(a)), bfhi(b-bfhif(b)), bfhi(c-bfhif(c)), bfhi(d-bfhif(d)) };
            *(short4v*)(hbw + si)        = hi;
            *(short4v*)(hbw + 1024 + si) = lo;
        }
    }
    __syncthreads();   // wl(L0) staged + hb(input) visible

    float hout[16];

    auto do_layer = [&](LayerParams p, const short* __restrict__ wlofrag, bool writeback){
        bf16x8 bhh[2], bhl[2];
        #pragma unroll
        for (int ks = 0; ks < 2; ++ks){
            int si = ((c16 << 6) + ks*32 + (q << 3)) ^ swz;
            bhh[ks] = *(const bf16x8*)(hbw + si);
            bhl[ks] = *(const bf16x8*)(hbw + 1024 + si);
        }
        f32x4 acc[16];
        #pragma unroll
        for (int mt = 0; mt < 16; ++mt)
            acc[mt] = *(const f32x4*)(p.bi + mt*16 + (q << 2));
        #pragma unroll
        for (int mt = 0; mt < 16; ++mt){
            #pragma unroll
            for (int ks = 0; ks < 2; ++ks){
                int si = ((((mt << 4) + c16) << 6) + ks*32 + (q << 3)) ^ swz;
                bf16x8 whi = *(const bf16x8*)(wl + si);
                bf16x8 wlo = *(const bf16x8*)(wlofrag + ((mt*2 + ks) << 9) + (lane << 3));
                acc[mt] = __builtin_amdgcn_mfma_f32_16x16x32_bf16(whi, bhh[ks], acc[mt], 0, 0, 0);
                acc[mt] = __builtin_amdgcn_mfma_f32_16x16x32_bf16(whi, bhl[ks], acc[mt], 0, 0, 0);
                acc[mt] = __builtin_amdgcn_mfma_f32_16x16x32_bf16(wlo, bhh[ks], acc[mt], 0, 0, 0);
            }
        }
        float sm = 0.f, sq = 0.f;
        #pragma unroll
        for (int mt = 0; mt < 16; ++mt){
            #pragma unroll
            for (int r = 0; r < 4; ++r){ float v = acc[mt][r]; sm += v; sq += v*v; }
        }
        sm += __shfl_xor(sm, 16); sm += __shfl_xor(sm, 32);
        sq += __shfl_xor(sq, 16); sq += __shfl_xor(sq, 32);
        const float m   = sm * (1.0f/256.0f);
        const float var = (sq - 256.0f*m*m) * (1.0f/255.0f);
        const float inv = frcp(sqrtf(fmaxf(var, 0.0f)) + EPS);

        float cx[16], oo[16];
        #pragma unroll
        for (int mt4 = 0; mt4 < 4; ++mt4){
            const f32x4 giI = *(const f32x4*)(p.gi   +       mt4*16 + (q << 2));
            const f32x4 giO = *(const f32x4*)(p.gi   + 128 + mt4*16 + (q << 2));
            const f32x4 giG = *(const f32x4*)(p.gi   + 192 + mt4*16 + (q << 2));
            const f32x4 adI = *(const f32x4*)(p.addv +       mt4*16 + (q << 2));
            const f32x4 adO = *(const f32x4*)(p.addv + 128 + mt4*16 + (q << 2));
            const f32x4 adG = *(const f32x4*)(p.addv + 192 + mt4*16 + (q << 2));
            #pragma unroll
            for (int r = 0; r < 4; ++r){
                const float i_ = (acc[mt4   ][r]-m)*inv*giI[r] + adI[r];
                const float o_ = (acc[mt4+ 8][r]-m)*inv*giO[r] + adO[r];
                const float g_ = (acc[mt4+12][r]-m)*inv*giG[r] + adG[r];
                cx[mt4*4+r] = fsig(i_) * ftanh(g_);
                oo[mt4*4+r] = o_;
            }
        }
        float s2 = 0.f, q2 = 0.f;
        #pragma unroll
        for (int t = 0; t < 16; ++t){ s2 += cx[t]; q2 += cx[t]*cx[t]; }
        s2 += __shfl_xor(s2, 16); s2 += __shfl_xor(s2, 32);
        q2 += __shfl_xor(q2, 16); q2 += __shfl_xor(q2, 32);
        const float mc = s2 * (1.0f/64.0f);
        const float vc = (q2 - 64.0f*mc*mc) * (1.0f/63.0f);
        const float ic = frcp(sqrtf(fmaxf(vc, 0.0f)) + EPS);
        #pragma unroll
        for (int mt4 = 0; mt4 < 4; ++mt4){
            const f32x4 gc4 = *(const f32x4*)(p.gc + mt4*16 + (q << 2));
            const f32x4 bc4 = *(const f32x4*)(p.bc + mt4*16 + (q << 2));
            #pragma unroll
            for (int r = 0; r < 4; ++r)
                hout[mt4*4+r] = fsig(oo[mt4*4+r]) * ftanh((cx[mt4*4+r]-mc)*ic*gc4[r] + bc4[r]);
        }
        if (writeback){
            #pragma unroll
            for (int mt4 = 0; mt4 < 4; ++mt4){
                int si = ((c16 << 6) + mt4*16 + (q << 2)) ^ swz;
                float a = hout[mt4*4+0], b = hout[mt4*4+1], c = hout[mt4*4+2], d = hout[mt4*4+3];
                short4v hi = { bfhi(a), bfhi(b), bfhi(c), bfhi(d) };
                short4v lo = { bfhi(a-bfhif(a)), bfhi(b-bfhif(b)), bfhi(c-bfhif(c)), bfhi(d-bfhif(d)) };
                *(short4v*)(hbw + si)        = hi;
                *(short4v*)(hbw + 1024 + si) = lo;
            }
        }
    };

    do_layer({bi0, gi0, ws + 1056, gc0, bc0}, SB,          true);
    __syncthreads();   // all waves done with wl(L0); hb(h1) visible
    stage_hi(Wi1);
    __syncthreads();   // wl(L1) staged
    do_layer({bi1, gi1, ws + 1312, gc1, bc1}, SB + 16384, false);

    float o = 0.f;
    #pragma unroll
    for (int mt4 = 0; mt4 < 4; ++mt4){
        const f32x4 wo4 = *(const f32x4*)(Wo + mt4*16 + (q << 2));
        #pragma unroll
        for (int r = 0; r < 4; ++r) o += hout[mt4*4+r]*wo4[r];
    }
    o += __shfl_xor(o, 16); o += __shfl_xor(o, 32);
    if (q == 0 && row <= P) out[row] = o + bo[0];
}

// ---------------- fallback: round-3 proven kernel (whi+wlo both in LDS, 96 KB) ----------------
__global__ __launch_bounds__(512, 2) void fwd_lds(
    const float* __restrict__ x,
    const float* __restrict__ W1, const float* __restrict__ b1,
    const float* __restrict__ g1, const float* __restrict__ be1,
    const float* __restrict__ Wi0, const float* __restrict__ bi0,
    const float* __restrict__ gi0, const float* __restrict__ gc0, const float* __restrict__ bc0,
    const float* __restrict__ Wi1, const float* __restrict__ bi1,
    const float* __restrict__ gi1, const float* __restrict__ gc1, const float* __restrict__ bc1,
    const float* __restrict__ Wo, const float* __restrict__ bo,
    const float* __restrict__ ws, float* __restrict__ out, int P)
{
    __shared__ short wl[32768];
    __shared__ short hb[16384];

    const int tid  = threadIdx.x;
    const int wid  = tid >> 6;
    const int lane = tid & 63;
    const int c16  = lane & 15;
    const int q    = lane >> 4;
    const int row  = blockIdx.x*128 + wid*16 + c16;
    short* hbw = hb + wid*2048;
    const int swz = (c16 & 7) << 3;

    auto stage = [&](const float* __restrict__ W){
        #pragma unroll
        for (int i = 0; i < 8; ++i){
            int idx = i*512 + tid;
            int g = idx >> 4, k0 = (idx & 15) << 2;
            f32x4 w4 = *(const f32x4*)(W + (idx << 2));
            int si = ((g << 6) + k0) ^ ((g & 7) << 3);
            short4v hi = { bfhi(w4[0]), bfhi(w4[1]), bfhi(w4[2]), bfhi(w4[3]) };
            short4v lo = { bfhi(w4[0]-bfhif(w4[0])), bfhi(w4[1]-bfhif(w4[1])),
                           bfhi(w4[2]-bfhif(w4[2])), bfhi(w4[3]-bfhif(w4[3])) };
            *(short4v*)(wl + si)         = hi;
            *(short4v*)(wl + 16384 + si) = lo;
        }
    };

    stage(Wi0);

    float xv = 0.0f;
    if (row < P) xv = x[row];
    else if (row == P) xv = ws[0];

    {
        const int cb = q << 4;
        float h[16]; float sm = 0.f, sq = 0.f;
        #pragma unroll
        for (int j = 0; j < 16; ++j){
            float v = xv*W1[cb+j] + b1[cb+j];
            h[j] = v; sm += v; sq += v*v;
        }
        sm += __shfl_xor(sm, 16); sm += __shfl_xor(sm, 32);
        sq += __shfl_xor(sq, 16); sq += __shfl_xor(sq, 32);
        const float m   = sm * (1.0f/64.0f);
        const float var = (sq - 64.0f*m*m) * (1.0f/63.0f);
        const float inv = frcp(sqrtf(fmaxf(var, 0.0f)) + EPS);
        #pragma unroll
        for (int j = 0; j < 16; ++j)
            h[j] = ftanh((h[j]-m)*inv*g1[cb+j] + be1[cb+j]);
        #pragma unroll
        for (int j4 = 0; j4 < 4; ++j4){
            int si = ((c16 << 6) + cb + (j4 << 2)) ^ swz;
            short4v hi = { bfhi(h[j4*4+0]), bfhi(h[j4*4+1]), bfhi(h[j4*4+2]), bfhi(h[j4*4+3]) };
            short4v lo = { bfhi(h[j4*4+0]-bfhif(h[j4*4+0])), bfhi(h[j4*4+1]-bfhif(h[j4*4+1])),
                           bfhi(h[j4*4+2]-bfhif(h[j4*4+2])), bfhi(h[j4*4+3]-bfhif(h[j4*4+3])) };
            *(short4v*)(hbw + si)        = hi;
            *(short4v*)(hbw + 1024 + si) = lo;
        }
    }
    __syncthreads();

    float hout[16];

    auto do_layer = [&](LayerParams p, bool writeback){
        bf16x8 bhh[2], bhl[2];
        #pragma unroll
        for (int ks = 0; ks < 2; ++ks){
            int si = ((c16 << 6) + ks*32 + (q << 3)) ^ swz;
            bhh[ks] = *(const bf16x8*)(hbw + si);
            bhl[ks] = *(const bf16x8*)(hbw + 1024 + si);
        }
        f32x4 acc[16];
        #pragma unroll
        for (int mt = 0; mt < 16; ++mt)
            acc[mt] = *(const f32x4*)(p.bi + mt*16 + (q << 2));
        #pragma unroll
        for (int mt = 0; mt < 16; ++mt){
            #pragma unroll
            for (int ks = 0; ks < 2; ++ks){
                int si = ((((mt << 4) + c16) << 6) + ks*32 + (q << 3)) ^ swz;
                bf16x8 whi = *(const bf16x8*)(wl + si);
                bf16x8 wlo = *(const bf16x8*)(wl + 16384 + si);
                acc[mt] = __builtin_amdgcn_mfma_f32_16x16x32_bf16(whi, bhh[ks], acc[mt], 0, 0, 0);
                acc[mt] = __builtin_amdgcn_mfma_f32_16x16x32_bf16(whi, bhl[ks], acc[mt], 0, 0, 0);
                acc[mt] = __builtin_amdgcn_mfma_f32_16x16x32_bf16(wlo, bhh[ks], acc[mt], 0, 0, 0);
            }
        }
        float sm = 0.f, sq = 0.f;
        #pragma unroll
        for (int mt = 0; mt < 16; ++mt){
            #pragma unroll
            for (int r = 0; r < 4; ++r){ float v = acc[mt][r]; sm += v; sq += v*v; }
        }
        sm += __shfl_xor(sm, 16); sm += __shfl_xor(sm, 32);
        sq += __shfl_xor(sq, 16); sq += __shfl_xor(sq, 32);
        const float m   = sm * (1.0f/256.0f);
        const float var = (sq - 256.0f*m*m) * (1.0f/255.0f);
        const float inv = frcp(sqrtf(fmaxf(var, 0.0f)) + EPS);

        float cx[16], oo[16];
        #pragma unroll
        for (int mt4 = 0; mt4 < 4; ++mt4){
            const f32x4 giI = *(const f32x4*)(p.gi   +       mt4*16 + (q << 2));
            const f32x4 giO = *(const f32x4*)(p.gi   + 128 + mt4*16 + (q << 2));
            const f32x4 giG = *(const f32x4*)(p.gi   + 192 + mt4*16 + (q << 2));
            const f32x4 adI = *(const f32x4*)(p.addv +       mt4*16 + (q << 2));
            const f32x4 adO = *(const f32x4*)(p.addv + 128 + mt4*16 + (q << 2));
            const f32x4 adG = *(const f32x4*)(p.addv + 192 + mt4*16 + (q << 2));
            #pragma unroll
            for (int r = 0; r < 4; ++r){
                const float i_ = (acc[mt4   ][r]-m)*inv*giI[r] + adI[r];
                const float o_ = (acc[mt4+ 8][r]-m)*inv*giO[r] + adO[r];
                const float g_ = (acc[mt4+12][r]-m)*inv*giG[r] + adG[r];
                cx[mt4*4+r] = fsig(i_) * ftanh(g_);
                oo[mt4*4+r] = o_;
            }
        }
        float s2 = 0.f, q2 = 0.f;
        #pragma unroll
        for (int t = 0; t < 16; ++t){ s2 += cx[t]; q2 += cx[t]*cx[t]; }
        s2 += __shfl_xor(s2, 16); s2 += __shfl_xor(s2, 32);
        q2 += __shfl_xor(q2, 16); q2 += __shfl_xor(q2, 32);
        const float mc = s2 * (1.0f/64.0f);
        const float vc = (q2 - 64.0f*mc*mc) * (1.0f/63.0f);
        const float ic = frcp(sqrtf(fmaxf(vc, 0.0f)) + EPS);
        #pragma unroll
        for (int mt4 = 0; mt4 < 4; ++mt4){
            const f32x4 gc4 = *(const f32x4*)(p.gc + mt4*16 + (q << 2));
            const f32x4 bc4 = *(const f32x4*)(p.bc + mt4*16 + (q << 2));
            #pragma unroll
            for (int r = 0; r < 4; ++r)
                hout[mt4*4+r] = fsig(oo[mt4*4+r]) * ftanh((cx[mt4*4+r]-mc)*ic*gc4[r] + bc4[r]);
        }
        if (writeback){
            #pragma unroll
            for (int mt4 = 0; mt4 < 4; ++mt4){
                int si = ((c16 << 6) + mt4*16 + (q << 2)) ^ swz;
                float a = hout[mt4*4+0], b = hout[mt4*4+1], c = hout[mt4*4+2], d = hout[mt4*4+3];
                short4v hi = { bfhi(a), bfhi(b), bfhi(c), bfhi(d) };
                short4v lo = { bfhi(a-bfhif(a)), bfhi(b-bfhif(b)), bfhi(c-bfhif(c)), bfhi(d-bfhif(d)) };
                *(short4v*)(hbw + si)        = hi;
                *(short4v*)(hbw + 1024 + si) = lo;
            }
        }
    };

    do_layer({bi0, gi0, ws + 1056, gc0, bc0}, true);
    __syncthreads();
    stage(Wi1);
    __syncthreads();
    do_layer({bi1, gi1, ws + 1312, gc1, bc1}, false);

    float o = 0.f;
    #pragma unroll
    for (int mt4 = 0; mt4 < 4; ++mt4){
        const f32x4 wo4 = *(const f32x4*)(Wo + mt4*16 + (q << 2));
        #pragma unroll
        for (int r = 0; r < 4; ++r) o += hout[mt4*4+r]*wo4[r];
    }
    o += __shfl_xor(o, 16); o += __shfl_xor(o, 32);
    if (q == 0 && row <= P) out[row] = o + bo[0];
}

extern "C" void kernel_launch(void* const* d_in, const int* in_sizes, int n_in,
                              void* d_out, int out_size, void* d_ws, size_t ws_size,
                              hipStream_t stream)
{
    (void)n_in; (void)out_size;
    const float* x     = (const float*)d_in[0];
    const float* W1    = (const float*)d_in[1];
    const float* b1    = (const float*)d_in[2];
    const float* g1    = (const float*)d_in[3];
    const float* be1   = (const float*)d_in[4];
    const float* l0_Wi = (const float*)d_in[5];
    const float* l0_bi = (const float*)d_in[6];
    const float* l0_bh = (const float*)d_in[8];
    const float* l0_gi = (const float*)d_in[9];
    const float* l0_bgi= (const float*)d_in[10];
    const float* l0_gh = (const float*)d_in[11];
    const float* l0_bgh= (const float*)d_in[12];
    const float* l0_gc = (const float*)d_in[13];
    const float* l0_bc = (const float*)d_in[14];
    const float* l1_Wi = (const float*)d_in[15];
    const float* l1_bi = (const float*)d_in[16];
    const float* l1_bh = (const float*)d_in[18];
    const float* l1_gi = (const float*)d_in[19];
    const float* l1_bgi= (const float*)d_in[20];
    const float* l1_gh = (const float*)d_in[21];
    const float* l1_bgh= (const float*)d_in[22];
    const float* l1_gc = (const float*)d_in[23];
    const float* l1_bc = (const float*)d_in[24];
    const float* Wo    = (const float*)d_in[25];
    const float* bo    = (const float*)d_in[26];

    int P = in_sizes[0];
    int B = P + 1;
    float* ws  = (float*)d_ws;
    float* out = (float*)d_out;

    mean_part<<<1024, 256, 0, stream>>>(x, P, ws + 16);
    mean_fin<<<1, 1024, 0, stream>>>(ws + 16, ws, P);
    precomp_add<<<2, 256, 0, stream>>>(
        l0_bh, l0_gh, l0_bgh, l0_bgi,
        l1_bh, l1_gh, l1_bgh, l1_bgi, ws);

    if (ws_size >= (size_t)WS_NEED){
        precomp_wlo<<<2, 256, 0, stream>>>(l0_Wi, l1_Wi, ws);
        fwd_stream<<<(B + 127)/128, 512, 0, stream>>>(
            x, W1, b1, g1, be1,
            l0_Wi, l0_bi, l0_gi, l0_gc, l0_bc,
            l1_Wi, l1_bi, l1_gi, l1_gc, l1_bc,
            Wo, bo, ws, out, P);
    } else {
        fwd_lds<<<(B + 127)/128, 512, 0, stream>>>(
            x, W1, b1, g1, be1,
            l0_Wi, l0_bi, l0_gi, l0_gc, l0_bc,
            l1_Wi, l1_bi, l1_gi, l1_gc, l1_bc,
            Wo, bo, ws, out, P);
    }
}

// Round 7
// 308.588 us; speedup vs baseline: 1.0509x; 1.0509x over previous
//
#include <hip/hip_runtime.h>

#define EPS 1e-5f

typedef __attribute__((ext_vector_type(8))) short bf16x8;
typedef __attribute__((ext_vector_type(4))) short short4v;
typedef __attribute__((ext_vector_type(4))) float f32x4;

__device__ __forceinline__ float fexp(float x){ return __builtin_amdgcn_exp2f(x*1.4426950408889634f); }
__device__ __forceinline__ float frcp(float x){ return __builtin_amdgcn_rcpf(x); }
__device__ __forceinline__ float fsig(float x){ return frcp(1.0f + fexp(-x)); }
__device__ __forceinline__ float ftanh(float x){ return 1.0f - 2.0f*frcp(fexp(2.0f*x) + 1.0f); }

__device__ __forceinline__ short bfhi(float v){ return (short)(__float_as_uint(v) >> 16); }
__device__ __forceinline__ float bfhif(float v){ return __uint_as_float(__float_as_uint(v) & 0xFFFF0000u); }

// ws float layout:
//   [0]            mean_x
//   [16..1040)     mean partials
//   [1056..1312)   add0 ; [1312..1568) add1
// shorts region SB = (short*)(ws + 2048)  (only used when ws_size >= WS_NEED):
//   SB[0..16384)      wlo0 (MFMA A-fragment order, 2048 slots x 8 bf16)
//   SB[16384..32768)  wlo1
#define WS_NEED (2048*4 + 2*16384*2)   // 73728 bytes

// ---------------- mean(x) reduction (deterministic, 2-stage) ----------------
__global__ void mean_part(const float* __restrict__ x, int P, float* __restrict__ part)
{
    __shared__ float red[256];
    int tid = blockIdx.x*256 + threadIdx.x;
    float s = 0.0f;
    for (int i = tid; i < P; i += 256*1024) s += x[i];
    red[threadIdx.x] = s; __syncthreads();
    for (int w = 128; w > 0; w >>= 1){
        if (threadIdx.x < w) red[threadIdx.x] += red[threadIdx.x + w];
        __syncthreads();
    }
    if (threadIdx.x == 0) part[blockIdx.x] = red[0];
}

__global__ void mean_fin(const float* __restrict__ part, float* __restrict__ ws, int P)
{
    __shared__ float red[1024];
    int t = threadIdx.x;
    red[t] = part[t]; __syncthreads();
    for (int w = 512; w > 0; w >>= 1){
        if (t < w) red[t] += red[t + w];
        __syncthreads();
    }
    if (t == 0) ws[0] = red[0] / (float)P;
}

// ---------------- add-vector precompute: add = LN(bh,gh,bgh) + bgi ----------------
__global__ void precomp_add(
    const float* __restrict__ bh0, const float* __restrict__ gh0,
    const float* __restrict__ bgh0, const float* __restrict__ bgi0,
    const float* __restrict__ bh1, const float* __restrict__ gh1,
    const float* __restrict__ bgh1, const float* __restrict__ bgi1,
    float* __restrict__ ws)
{
    const int l = blockIdx.x;
    const float* bh  = l ? bh1  : bh0;
    const float* gh  = l ? gh1  : gh0;
    const float* bgh = l ? bgh1 : bgh0;
    const float* bgi = l ? bgi1 : bgi0;
    float* add = ws + 1056 + l*256;
    int t = threadIdx.x;

    __shared__ float r1[256], r2[256];
    float v = bh[t];
    r1[t] = v; r2[t] = v*v; __syncthreads();
    for (int w = 128; w > 0; w >>= 1){
        if (t < w){ r1[t] += r1[t+w]; r2[t] += r2[t+w]; }
        __syncthreads();
    }
    float m   = r1[0] * (1.0f/256.0f);
    float var = (r2[0] - 256.0f*m*m) * (1.0f/255.0f);
    float s   = sqrtf(fmaxf(var, 0.0f));
    float c   = (v - m) * frcp(s + EPS) * gh[t] + bgh[t];
    add[t] = c + bgi[t];
}

// ---------------- wlo fragment images ----------------
// 2048 slots per layer: slot = (mt*2+ks)*64 + lane ; lane holds 8 bf16-lo:
//   g = mt*16 + (lane&15), k = ks*32 + (lane>>4)*8 + j     (mt<16, ks<2)
__global__ void precomp_wlo(const float* __restrict__ Wi0, const float* __restrict__ Wi1,
                            float* __restrict__ ws)
{
    const int l = blockIdx.x;
    const float* Wi = l ? Wi1 : Wi0;
    short* wlos = (short*)(ws + 2048) + l*16384;
    int t = threadIdx.x;
    for (int i = 0; i < 8; ++i){               // 8*256 = 2048 slots
        int slot = i*256 + t;                   // 0..2047
        int lane = slot & 63, mtks = slot >> 6; // mtks 0..31
        int mt = mtks >> 1, ks = mtks & 1;
        int g  = (mt << 4) + (lane & 15);
        int k  = (ks << 5) + ((lane >> 4) << 3);
        short tmp[8];
        #pragma unroll
        for (int j = 0; j < 8; ++j){
            float w = Wi[(g << 6) + k + j];
            tmp[j] = bfhi(w - bfhif(w));
        }
        short4v a = { tmp[0], tmp[1], tmp[2], tmp[3] };
        short4v b = { tmp[4], tmp[5], tmp[6], tmp[7] };
        *(short4v*)(wlos + slot*8)     = a;
        *(short4v*)(wlos + slot*8 + 4) = b;
    }
}

// ================= shared device helpers =================
struct LayerParams { const float *bi, *gi, *addv, *gc, *bc; };

// ---------------- fast path: whi in LDS (32 KB), wlo streamed from global ----------------
// Register-lean: the whole layer is computed IN PLACE over acc[16] (no cx/oo/hout
// arrays). After the layer, acc[0..3] holds this wave's h-output.
__global__ __launch_bounds__(512, 4) void fwd_stream(
    const float* __restrict__ x,
    const float* __restrict__ W1, const float* __restrict__ b1,
    const float* __restrict__ g1, const float* __restrict__ be1,
    const float* __restrict__ Wi0, const float* __restrict__ bi0,
    const float* __restrict__ gi0, const float* __restrict__ gc0, const float* __restrict__ bc0,
    const float* __restrict__ Wi1, const float* __restrict__ bi1,
    const float* __restrict__ gi1, const float* __restrict__ gc1, const float* __restrict__ bc1,
    const float* __restrict__ Wo, const float* __restrict__ bo,
    const float* __restrict__ ws, float* __restrict__ out, int P)
{
    __shared__ short wl[16384];   // whi of current layer (32 KB)
    __shared__ short hb[16384];   // [wave][part][row16][cell64] swizzled (32 KB)

    const int tid  = threadIdx.x;
    const int wid  = tid >> 6;
    const int lane = tid & 63;
    const int c16  = lane & 15;
    const int q    = lane >> 4;
    const int row  = blockIdx.x*128 + wid*16 + c16;
    short* hbw = hb + wid*2048;
    const int swz = (c16 & 7) << 3;
    const short* SB = (const short*)(ws + 2048);

    auto stage_hi = [&](const float* __restrict__ W){
        #pragma unroll
        for (int i = 0; i < 8; ++i){
            int idx = i*512 + tid;                  // float4 chunk 0..4095
            int g = idx >> 4, k0 = (idx & 15) << 2;
            f32x4 w4 = *(const f32x4*)(W + (idx << 2));
            int si = ((g << 6) + k0) ^ ((g & 7) << 3);
            short4v hi = { bfhi(w4[0]), bfhi(w4[1]), bfhi(w4[2]), bfhi(w4[3]) };
            *(short4v*)(wl + si) = hi;
        }
    };

    stage_hi(Wi0);

    float xv = 0.0f;
    if (row < P) xv = x[row];
    else if (row == P) xv = ws[0];

    // ---- input layer: h = tanh(LN64(x*W1 + b1)); write hb, h dies after ----
    {
        float h[16];
        float sm = 0.f, sq = 0.f;
        #pragma unroll
        for (int mt4 = 0; mt4 < 4; ++mt4){
            const f32x4 w14 = *(const f32x4*)(W1 + mt4*16 + (q << 2));
            const f32x4 b14 = *(const f32x4*)(b1 + mt4*16 + (q << 2));
            #pragma unroll
            for (int r = 0; r < 4; ++r){
                float v = xv*w14[r] + b14[r];
                h[mt4*4+r] = v; sm += v; sq += v*v;
            }
        }
        sm += __shfl_xor(sm, 16); sm += __shfl_xor(sm, 32);
        sq += __shfl_xor(sq, 16); sq += __shfl_xor(sq, 32);
        const float m   = sm * (1.0f/64.0f);
        const float var = (sq - 64.0f*m*m) * (1.0f/63.0f);
        const float inv = frcp(sqrtf(fmaxf(var, 0.0f)) + EPS);
        #pragma unroll
        for (int mt4 = 0; mt4 < 4; ++mt4){
            const f32x4 g14  = *(const f32x4*)(g1  + mt4*16 + (q << 2));
            const f32x4 be14 = *(const f32x4*)(be1 + mt4*16 + (q << 2));
            #pragma unroll
            for (int r = 0; r < 4; ++r)
                h[mt4*4+r] = ftanh((h[mt4*4+r]-m)*inv*g14[r] + be14[r]);
        }
        #pragma unroll
        for (int mt4 = 0; mt4 < 4; ++mt4){
            int si = ((c16 << 6) + mt4*16 + (q << 2)) ^ swz;
            float a = h[mt4*4+0], b = h[mt4*4+1], c = h[mt4*4+2], d = h[mt4*4+3];
            short4v hi = { bfhi(a), bfhi(b), bfhi(c), bfhi(d) };
            short4v lo = { bfhi(a-bfhif(a)), bfhi(b-bfhif(b)), bfhi(c-bfhif(c)), bfhi(d-bfhif(d)) };
            *(short4v*)(hbw + si)        = hi;
            *(short4v*)(hbw + 1024 + si) = lo;
        }
    }
    __syncthreads();   // wl(L0) staged + hb(input) visible

    f32x4 acc[16];     // gate accumulators; after do_layer, acc[0..3] = h-out

    auto do_layer = [&](LayerParams p, const short* __restrict__ wlofrag, bool writeback){
        bf16x8 bhh[2], bhl[2];
        #pragma unroll
        for (int ks = 0; ks < 2; ++ks){
            int si = ((c16 << 6) + ks*32 + (q << 3)) ^ swz;
            bhh[ks] = *(const bf16x8*)(hbw + si);
            bhl[ks] = *(const bf16x8*)(hbw + 1024 + si);
        }
        #pragma unroll
        for (int mt = 0; mt < 16; ++mt)
            acc[mt] = *(const f32x4*)(p.bi + mt*16 + (q << 2));
        #pragma unroll
        for (int mt = 0; mt < 16; ++mt){
            #pragma unroll
            for (int ks = 0; ks < 2; ++ks){
                int si = ((((mt << 4) + c16) << 6) + ks*32 + (q << 3)) ^ swz;
                bf16x8 whi = *(const bf16x8*)(wl + si);
                bf16x8 wlo = *(const bf16x8*)(wlofrag + ((mt*2 + ks) << 9) + (lane << 3));
                acc[mt] = __builtin_amdgcn_mfma_f32_16x16x32_bf16(whi, bhh[ks], acc[mt], 0, 0, 0);
                acc[mt] = __builtin_amdgcn_mfma_f32_16x16x32_bf16(whi, bhl[ks], acc[mt], 0, 0, 0);
                acc[mt] = __builtin_amdgcn_mfma_f32_16x16x32_bf16(wlo, bhh[ks], acc[mt], 0, 0, 0);
            }
        }
        // LN256 stats
        float sm = 0.f, sq = 0.f;
        #pragma unroll
        for (int mt = 0; mt < 16; ++mt){
            #pragma unroll
            for (int r = 0; r < 4; ++r){ float v = acc[mt][r]; sm += v; sq += v*v; }
        }
        sm += __shfl_xor(sm, 16); sm += __shfl_xor(sm, 32);
        sq += __shfl_xor(sq, 16); sq += __shfl_xor(sq, 32);
        const float m   = sm * (1.0f/256.0f);
        const float var = (sq - 256.0f*m*m) * (1.0f/255.0f);
        const float inv = frcp(sqrtf(fmaxf(var, 0.0f)) + EPS);

        // gates in place: acc[mt4] <- cx = sig(i)*tanh(g); acc[mt4+8] <- o
        // (i = mt 0..3, f = 4..7 stats-only, o = 8..11, g = 12..15)
        #pragma unroll
        for (int mt4 = 0; mt4 < 4; ++mt4){
            const f32x4 giI = *(const f32x4*)(p.gi   +       mt4*16 + (q << 2));
            const f32x4 giO = *(const f32x4*)(p.gi   + 128 + mt4*16 + (q << 2));
            const f32x4 giG = *(const f32x4*)(p.gi   + 192 + mt4*16 + (q << 2));
            const f32x4 adI = *(const f32x4*)(p.addv +       mt4*16 + (q << 2));
            const f32x4 adO = *(const f32x4*)(p.addv + 128 + mt4*16 + (q << 2));
            const f32x4 adG = *(const f32x4*)(p.addv + 192 + mt4*16 + (q << 2));
            #pragma unroll
            for (int r = 0; r < 4; ++r){
                const float i_ = (acc[mt4   ][r]-m)*inv*giI[r] + adI[r];
                const float o_ = (acc[mt4+ 8][r]-m)*inv*giO[r] + adO[r];
                const float g_ = (acc[mt4+12][r]-m)*inv*giG[r] + adG[r];
                acc[mt4   ][r] = fsig(i_) * ftanh(g_);
                acc[mt4+ 8][r] = o_;
            }
        }
        // LN64 over cx (acc[0..3]), then acc[mt4] <- sig(oo)*tanh(LN(cx))
        float s2 = 0.f, q2 = 0.f;
        #pragma unroll
        for (int mt4 = 0; mt4 < 4; ++mt4){
            #pragma unroll
            for (int r = 0; r < 4; ++r){ float v = acc[mt4][r]; s2 += v; q2 += v*v; }
        }
        s2 += __shfl_xor(s2, 16); s2 += __shfl_xor(s2, 32);
        q2 += __shfl_xor(q2, 16); q2 += __shfl_xor(q2, 32);
        const float mc = s2 * (1.0f/64.0f);
        const float vc = (q2 - 64.0f*mc*mc) * (1.0f/63.0f);
        const float ic = frcp(sqrtf(fmaxf(vc, 0.0f)) + EPS);
        #pragma unroll
        for (int mt4 = 0; mt4 < 4; ++mt4){
            const f32x4 gc4 = *(const f32x4*)(p.gc + mt4*16 + (q << 2));
            const f32x4 bc4 = *(const f32x4*)(p.bc + mt4*16 + (q << 2));
            #pragma unroll
            for (int r = 0; r < 4; ++r)
                acc[mt4][r] = fsig(acc[mt4+8][r]) * ftanh((acc[mt4][r]-mc)*ic*gc4[r] + bc4[r]);
        }
        if (writeback){
            #pragma unroll
            for (int mt4 = 0; mt4 < 4; ++mt4){
                int si = ((c16 << 6) + mt4*16 + (q << 2)) ^ swz;
                float a = acc[mt4][0], b = acc[mt4][1], c = acc[mt4][2], d = acc[mt4][3];
                short4v hi = { bfhi(a), bfhi(b), bfhi(c), bfhi(d) };
                short4v lo = { bfhi(a-bfhif(a)), bfhi(b-bfhif(b)), bfhi(c-bfhif(c)), bfhi(d-bfhif(d)) };
                *(short4v*)(hbw + si)        = hi;
                *(short4v*)(hbw + 1024 + si) = lo;
            }
        }
    };

    do_layer({bi0, gi0, ws + 1056, gc0, bc0}, SB,          true);
    __syncthreads();   // all waves done with wl(L0); hb(h1) visible
    stage_hi(Wi1);
    __syncthreads();   // wl(L1) staged
    do_layer({bi1, gi1, ws + 1312, gc1, bc1}, SB + 16384, false);

    // output: out = h2 . Wo + bo  (h2 in acc[0..3])
    float o = 0.f;
    #pragma unroll
    for (int mt4 = 0; mt4 < 4; ++mt4){
        const f32x4 wo4 = *(const f32x4*)(Wo + mt4*16 + (q << 2));
        #pragma unroll
        for (int r = 0; r < 4; ++r) o += acc[mt4][r]*wo4[r];
    }
    o += __shfl_xor(o, 16); o += __shfl_xor(o, 32);
    if (q == 0 && row <= P) out[row] = o + bo[0];
}

// ---------------- fallback: round-3 proven kernel (whi+wlo both in LDS, 96 KB) ----------------
__global__ __launch_bounds__(512, 2) void fwd_lds(
    const float* __restrict__ x,
    const float* __restrict__ W1, const float* __restrict__ b1,
    const float* __restrict__ g1, const float* __restrict__ be1,
    const float* __restrict__ Wi0, const float* __restrict__ bi0,
    const float* __restrict__ gi0, const float* __restrict__ gc0, const float* __restrict__ bc0,
    const float* __restrict__ Wi1, const float* __restrict__ bi1,
    const float* __restrict__ gi1, const float* __restrict__ gc1, const float* __restrict__ bc1,
    const float* __restrict__ Wo, const float* __restrict__ bo,
    const float* __restrict__ ws, float* __restrict__ out, int P)
{
    __shared__ short wl[32768];
    __shared__ short hb[16384];

    const int tid  = threadIdx.x;
    const int wid  = tid >> 6;
    const int lane = tid & 63;
    const int c16  = lane & 15;
    const int q    = lane >> 4;
    const int row  = blockIdx.x*128 + wid*16 + c16;
    short* hbw = hb + wid*2048;
    const int swz = (c16 & 7) << 3;

    auto stage = [&](const float* __restrict__ W){
        #pragma unroll
        for (int i = 0; i < 8; ++i){
            int idx = i*512 + tid;
            int g = idx >> 4, k0 = (idx & 15) << 2;
            f32x4 w4 = *(const f32x4*)(W + (idx << 2));
            int si = ((g << 6) + k0) ^ ((g & 7) << 3);
            short4v hi = { bfhi(w4[0]), bfhi(w4[1]), bfhi(w4[2]), bfhi(w4[3]) };
            short4v lo = { bfhi(w4[0]-bfhif(w4[0])), bfhi(w4[1]-bfhif(w4[1])),
                           bfhi(w4[2]-bfhif(w4[2])), bfhi(w4[3]-bfhif(w4[3])) };
            *(short4v*)(wl + si)         = hi;
            *(short4v*)(wl + 16384 + si) = lo;
        }
    };

    stage(Wi0);

    float xv = 0.0f;
    if (row < P) xv = x[row];
    else if (row == P) xv = ws[0];

    {
        const int cb = q << 4;
        float h[16]; float sm = 0.f, sq = 0.f;
        #pragma unroll
        for (int j = 0; j < 16; ++j){
            float v = xv*W1[cb+j] + b1[cb+j];
            h[j] = v; sm += v; sq += v*v;
        }
        sm += __shfl_xor(sm, 16); sm += __shfl_xor(sm, 32);
        sq += __shfl_xor(sq, 16); sq += __shfl_xor(sq, 32);
        const float m   = sm * (1.0f/64.0f);
        const float var = (sq - 64.0f*m*m) * (1.0f/63.0f);
        const float inv = frcp(sqrtf(fmaxf(var, 0.0f)) + EPS);
        #pragma unroll
        for (int j = 0; j < 16; ++j)
            h[j] = ftanh((h[j]-m)*inv*g1[cb+j] + be1[cb+j]);
        #pragma unroll
        for (int j4 = 0; j4 < 4; ++j4){
            int si = ((c16 << 6) + cb + (j4 << 2)) ^ swz;
            short4v hi = { bfhi(h[j4*4+0]), bfhi(h[j4*4+1]), bfhi(h[j4*4+2]), bfhi(h[j4*4+3]) };
            short4v lo = { bfhi(h[j4*4+0]-bfhif(h[j4*4+0])), bfhi(h[j4*4+1]-bfhif(h[j4*4+1])),
                           bfhi(h[j4*4+2]-bfhif(h[j4*4+2])), bfhi(h[j4*4+3]-bfhif(h[j4*4+3])) };
            *(short4v*)(hbw + si)        = hi;
            *(short4v*)(hbw + 1024 + si) = lo;
        }
    }
    __syncthreads();

    f32x4 acc[16];

    auto do_layer = [&](LayerParams p, bool writeback){
        bf16x8 bhh[2], bhl[2];
        #pragma unroll
        for (int ks = 0; ks < 2; ++ks){
            int si = ((c16 << 6) + ks*32 + (q << 3)) ^ swz;
            bhh[ks] = *(const bf16x8*)(hbw + si);
            bhl[ks] = *(const bf16x8*)(hbw + 1024 + si);
        }
        #pragma unroll
        for (int mt = 0; mt < 16; ++mt)
            acc[mt] = *(const f32x4*)(p.bi + mt*16 + (q << 2));
        #pragma unroll
        for (int mt = 0; mt < 16; ++mt){
            #pragma unroll
            for (int ks = 0; ks < 2; ++ks){
                int si = ((((mt << 4) + c16) << 6) + ks*32 + (q << 3)) ^ swz;
                bf16x8 whi = *(const bf16x8*)(wl + si);
                bf16x8 wlo = *(const bf16x8*)(wl + 16384 + si);
                acc[mt] = __builtin_amdgcn_mfma_f32_16x16x32_bf16(whi, bhh[ks], acc[mt], 0, 0, 0);
                acc[mt] = __builtin_amdgcn_mfma_f32_16x16x32_bf16(whi, bhl[ks], acc[mt], 0, 0, 0);
                acc[mt] = __builtin_amdgcn_mfma_f32_16x16x32_bf16(wlo, bhh[ks], acc[mt], 0, 0, 0);
            }
        }
        float sm = 0.f, sq = 0.f;
        #pragma unroll
        for (int mt = 0; mt < 16; ++mt){
            #pragma unroll
            for (int r = 0; r < 4; ++r){ float v = acc[mt][r]; sm += v; sq += v*v; }
        }
        sm += __shfl_xor(sm, 16); sm += __shfl_xor(sm, 32);
        sq += __shfl_xor(sq, 16); sq += __shfl_xor(sq, 32);
        const float m   = sm * (1.0f/256.0f);
        const float var = (sq - 256.0f*m*m) * (1.0f/255.0f);
        const float inv = frcp(sqrtf(fmaxf(var, 0.0f)) + EPS);

        #pragma unroll
        for (int mt4 = 0; mt4 < 4; ++mt4){
            const f32x4 giI = *(const f32x4*)(p.gi   +       mt4*16 + (q << 2));
            const f32x4 giO = *(const f32x4*)(p.gi   + 128 + mt4*16 + (q << 2));
            const f32x4 giG = *(const f32x4*)(p.gi   + 192 + mt4*16 + (q << 2));
            const f32x4 adI = *(const f32x4*)(p.addv +       mt4*16 + (q << 2));
            const f32x4 adO = *(const f32x4*)(p.addv + 128 + mt4*16 + (q << 2));
            const f32x4 adG = *(const f32x4*)(p.addv + 192 + mt4*16 + (q << 2));
            #pragma unroll
            for (int r = 0; r < 4; ++r){
                const float i_ = (acc[mt4   ][r]-m)*inv*giI[r] + adI[r];
                const float o_ = (acc[mt4+ 8][r]-m)*inv*giO[r] + adO[r];
                const float g_ = (acc[mt4+12][r]-m)*inv*giG[r] + adG[r];
                acc[mt4   ][r] = fsig(i_) * ftanh(g_);
                acc[mt4+ 8][r] = o_;
            }
        }
        float s2 = 0.f, q2 = 0.f;
        #pragma unroll
        for (int mt4 = 0; mt4 < 4; ++mt4){
            #pragma unroll
            for (int r = 0; r < 4; ++r){ float v = acc[mt4][r]; s2 += v; q2 += v*v; }
        }
        s2 += __shfl_xor(s2, 16); s2 += __shfl_xor(s2, 32);
        q2 += __shfl_xor(q2, 16); q2 += __shfl_xor(q2, 32);
        const float mc = s2 * (1.0f/64.0f);
        const float vc = (q2 - 64.0f*mc*mc) * (1.0f/63.0f);
        const float ic = frcp(sqrtf(fmaxf(vc, 0.0f)) + EPS);
        #pragma unroll
        for (int mt4 = 0; mt4 < 4; ++mt4){
            const f32x4 gc4 = *(const f32x4*)(p.gc + mt4*16 + (q << 2));
            const f32x4 bc4 = *(const f32x4*)(p.bc + mt4*16 + (q << 2));
            #pragma unroll
            for (int r = 0; r < 4; ++r)
                acc[mt4][r] = fsig(acc[mt4+8][r]) * ftanh((acc[mt4][r]-mc)*ic*gc4[r] + bc4[r]);
        }
        if (writeback){
            #pragma unroll
            for (int mt4 = 0; mt4 < 4; ++mt4){
                int si = ((c16 << 6) + mt4*16 + (q << 2)) ^ swz;
                float a = acc[mt4][0], b = acc[mt4][1], c = acc[mt4][2], d = acc[mt4][3];
                short4v hi = { bfhi(a), bfhi(b), bfhi(c), bfhi(d) };
                short4v lo = { bfhi(a-bfhif(a)), bfhi(b-bfhif(b)), bfhi(c-bfhif(c)), bfhi(d-bfhif(d)) };
                *(short4v*)(hbw + si)        = hi;
                *(short4v*)(hbw + 1024 + si) = lo;
            }
        }
    };

    do_layer({bi0, gi0, ws + 1056, gc0, bc0}, true);
    __syncthreads();
    stage(Wi1);
    __syncthreads();
    do_layer({bi1, gi1, ws + 1312, gc1, bc1}, false);

    float o = 0.f;
    #pragma unroll
    for (int mt4 = 0; mt4 < 4; ++mt4){
        const f32x4 wo4 = *(const f32x4*)(Wo + mt4*16 + (q << 2));
        #pragma unroll
        for (int r = 0; r < 4; ++r) o += acc[mt4][r]*wo4[r];
    }
    o += __shfl_xor(o, 16); o += __shfl_xor(o, 32);
    if (q == 0 && row <= P) out[row] = o + bo[0];
}

extern "C" void kernel_launch(void* const* d_in, const int* in_sizes, int n_in,
                              void* d_out, int out_size, void* d_ws, size_t ws_size,
                              hipStream_t stream)
{
    (void)n_in; (void)out_size;
    const float* x     = (const float*)d_in[0];
    const float* W1    = (const float*)d_in[1];
    const float* b1    = (const float*)d_in[2];
    const float* g1    = (const float*)d_in[3];
    const float* be1   = (const float*)d_in[4];
    const float* l0_Wi = (const float*)d_in[5];
    const float* l0_bi = (const float*)d_in[6];
    const float* l0_bh = (const float*)d_in[8];
    const float* l0_gi = (const float*)d_in[9];
    const float* l0_bgi= (const float*)d_in[10];
    const float* l0_gh = (const float*)d_in[11];
    const float* l0_bgh= (const float*)d_in[12];
    const float* l0_gc = (const float*)d_in[13];
    const float* l0_bc = (const float*)d_in[14];
    const float* l1_Wi = (const float*)d_in[15];
    const float* l1_bi = (const float*)d_in[16];
    const float* l1_bh = (const float*)d_in[18];
    const float* l1_gi = (const float*)d_in[19];
    const float* l1_bgi= (const float*)d_in[20];
    const float* l1_gh = (const float*)d_in[21];
    const float* l1_bgh= (const float*)d_in[22];
    const float* l1_gc = (const float*)d_in[23];
    const float* l1_bc = (const float*)d_in[24];
    const float* Wo    = (const float*)d_in[25];
    const float* bo    = (const float*)d_in[26];

    int P = in_sizes[0];
    int B = P + 1;
    float* ws  = (float*)d_ws;
    float* out = (float*)d_out;

    mean_part<<<1024, 256, 0, stream>>>(x, P, ws + 16);
    mean_fin<<<1, 1024, 0, stream>>>(ws + 16, ws, P);
    precomp_add<<<2, 256, 0, stream>>>(
        l0_bh, l0_gh, l0_bgh, l0_bgi,
        l1_bh, l1_gh, l1_bgh, l1_bgi, ws);

    if (ws_size >= (size_t)WS_NEED){
        precomp_wlo<<<2, 256, 0, stream>>>(l0_Wi, l1_Wi, ws);
        fwd_stream<<<(B + 127)/128, 512, 0, stream>>>(
            x, W1, b1, g1, be1,
            l0_Wi, l0_bi, l0_gi, l0_gc, l0_bc,
            l1_Wi, l1_bi, l1_gi, l1_gc, l1_bc,
            Wo, bo, ws, out, P);
    } else {
        fwd_lds<<<(B + 127)/128, 512, 0, stream>>>(
            x, W1, b1, g1, be1,
            l0_Wi, l0_bi, l0_gi, l0_gc, l0_bc,
            l1_Wi, l1_bi, l1_gi, l1_gc, l1_bc,
            Wo, bo, ws, out, P);
    }
}

// Round 8
// 261.982 us; speedup vs baseline: 1.2379x; 1.1779x over previous
//
#include <hip/hip_runtime.h>

#define EPS 1e-5f

typedef __attribute__((ext_vector_type(8))) short bf16x8;
typedef __attribute__((ext_vector_type(4))) short short4v;
typedef __attribute__((ext_vector_type(4))) float f32x4;

__device__ __forceinline__ float fexp(float x){ return __builtin_amdgcn_exp2f(x*1.4426950408889634f); }
__device__ __forceinline__ float frcp(float x){ return __builtin_amdgcn_rcpf(x); }
__device__ __forceinline__ float fsig(float x){ return frcp(1.0f + fexp(-x)); }
__device__ __forceinline__ float ftanh(float x){ return 1.0f - 2.0f*frcp(fexp(2.0f*x) + 1.0f); }

__device__ __forceinline__ short bfhi(float v){ return (short)(__float_as_uint(v) >> 16); }
__device__ __forceinline__ float bfhif(float v){ return __uint_as_float(__float_as_uint(v) & 0xFFFF0000u); }

// ws float layout:
//   [0]            mean_x
//   [16..1040)     mean partials
//   [1056..1312)   add0 ; [1312..1568) add1
// shorts region SB = (short*)(ws + 2048)  (only used when ws_size >= WS_NEED):
//   SB[0..16384)      wlo0 (MFMA A-fragment order, 2048 slots x 8 bf16)
//   SB[16384..32768)  wlo1
#define WS_NEED (2048*4 + 2*16384*2)   // 73728 bytes

// ---------------- mean(x) reduction (deterministic, 2-stage) ----------------
__global__ void mean_part(const float* __restrict__ x, int P, float* __restrict__ part)
{
    __shared__ float red[256];
    int tid = blockIdx.x*256 + threadIdx.x;
    float s = 0.0f;
    for (int i = tid; i < P; i += 256*1024) s += x[i];
    red[threadIdx.x] = s; __syncthreads();
    for (int w = 128; w > 0; w >>= 1){
        if (threadIdx.x < w) red[threadIdx.x] += red[threadIdx.x + w];
        __syncthreads();
    }
    if (threadIdx.x == 0) part[blockIdx.x] = red[0];
}

__global__ void mean_fin(const float* __restrict__ part, float* __restrict__ ws, int P)
{
    __shared__ float red[1024];
    int t = threadIdx.x;
    red[t] = part[t]; __syncthreads();
    for (int w = 512; w > 0; w >>= 1){
        if (t < w) red[t] += red[t + w];
        __syncthreads();
    }
    if (t == 0) ws[0] = red[0] / (float)P;
}

// ---------------- add-vector precompute: add = LN(bh,gh,bgh) + bgi ----------------
__global__ void precomp_add(
    const float* __restrict__ bh0, const float* __restrict__ gh0,
    const float* __restrict__ bgh0, const float* __restrict__ bgi0,
    const float* __restrict__ bh1, const float* __restrict__ gh1,
    const float* __restrict__ bgh1, const float* __restrict__ bgi1,
    float* __restrict__ ws)
{
    const int l = blockIdx.x;
    const float* bh  = l ? bh1  : bh0;
    const float* gh  = l ? gh1  : gh0;
    const float* bgh = l ? bgh1 : bgh0;
    const float* bgi = l ? bgi1 : bgi0;
    float* add = ws + 1056 + l*256;
    int t = threadIdx.x;

    __shared__ float r1[256], r2[256];
    float v = bh[t];
    r1[t] = v; r2[t] = v*v; __syncthreads();
    for (int w = 128; w > 0; w >>= 1){
        if (t < w){ r1[t] += r1[t+w]; r2[t] += r2[t+w]; }
        __syncthreads();
    }
    float m   = r1[0] * (1.0f/256.0f);
    float var = (r2[0] - 256.0f*m*m) * (1.0f/255.0f);
    float s   = sqrtf(fmaxf(var, 0.0f));
    float c   = (v - m) * frcp(s + EPS) * gh[t] + bgh[t];
    add[t] = c + bgi[t];
}

// ---------------- wlo fragment images ----------------
// 2048 slots per layer: slot = (mt*2+ks)*64 + lane ; lane holds 8 bf16-lo:
//   g = mt*16 + (lane&15), k = ks*32 + (lane>>4)*8 + j     (mt<16, ks<2)
__global__ void precomp_wlo(const float* __restrict__ Wi0, const float* __restrict__ Wi1,
                            float* __restrict__ ws)
{
    const int l = blockIdx.x;
    const float* Wi = l ? Wi1 : Wi0;
    short* wlos = (short*)(ws + 2048) + l*16384;
    int t = threadIdx.x;
    for (int i = 0; i < 8; ++i){               // 8*256 = 2048 slots
        int slot = i*256 + t;                   // 0..2047
        int lane = slot & 63, mtks = slot >> 6; // mtks 0..31
        int mt = mtks >> 1, ks = mtks & 1;
        int g  = (mt << 4) + (lane & 15);
        int k  = (ks << 5) + ((lane >> 4) << 3);
        short tmp[8];
        #pragma unroll
        for (int j = 0; j < 8; ++j){
            float w = Wi[(g << 6) + k + j];
            tmp[j] = bfhi(w - bfhif(w));
        }
        short4v a = { tmp[0], tmp[1], tmp[2], tmp[3] };
        short4v b = { tmp[4], tmp[5], tmp[6], tmp[7] };
        *(short4v*)(wlos + slot*8)     = a;
        *(short4v*)(wlos + slot*8 + 4) = b;
    }
}

// ================= shared device helpers =================
struct LayerParams { const float *bi, *gi, *addv, *gc, *bc; };

// ---------------- fast path: 256 threads = 4 waves = 64 rows/block ----------------
// whi in LDS (32 KB, swizzled); wlo streamed from global fragment image (L2).
// launch_bounds(256,3): VGPR cap ~170 (fits the proven ~168 live set, no spills),
// 3 blocks/CU, LDS 48 KB/block -> 144 KB/CU.
__global__ __launch_bounds__(256, 3) void fwd_stream(
    const float* __restrict__ x,
    const float* __restrict__ W1, const float* __restrict__ b1,
    const float* __restrict__ g1, const float* __restrict__ be1,
    const float* __restrict__ Wi0, const float* __restrict__ bi0,
    const float* __restrict__ gi0, const float* __restrict__ gc0, const float* __restrict__ bc0,
    const float* __restrict__ Wi1, const float* __restrict__ bi1,
    const float* __restrict__ gi1, const float* __restrict__ gc1, const float* __restrict__ bc1,
    const float* __restrict__ Wo, const float* __restrict__ bo,
    const float* __restrict__ ws, float* __restrict__ out, int P)
{
    __shared__ short wl[16384];   // whi of current layer (32 KB)
    __shared__ short hb[8192];    // [wave(4)][part(2)][row16][cell64] swizzled (16 KB)

    const int tid  = threadIdx.x;
    const int wid  = tid >> 6;
    const int lane = tid & 63;
    const int c16  = lane & 15;
    const int q    = lane >> 4;
    const int row  = blockIdx.x*64 + wid*16 + c16;
    short* hbw = hb + wid*2048;
    const int swz = (c16 & 7) << 3;
    const short* SB = (const short*)(ws + 2048);

    auto stage_hi = [&](const float* __restrict__ W){
        #pragma unroll
        for (int i = 0; i < 16; ++i){
            int idx = i*256 + tid;                  // float4 chunk 0..4095
            int g = idx >> 4, k0 = (idx & 15) << 2;
            f32x4 w4 = *(const f32x4*)(W + (idx << 2));
            int si = ((g << 6) + k0) ^ ((g & 7) << 3);
            short4v hi = { bfhi(w4[0]), bfhi(w4[1]), bfhi(w4[2]), bfhi(w4[3]) };
            *(short4v*)(wl + si) = hi;
        }
    };

    stage_hi(Wi0);

    float xv = 0.0f;
    if (row < P) xv = x[row];
    else if (row == P) xv = ws[0];

    // ---- input layer: h = tanh(LN64(x*W1 + b1)); write hb, h dies after ----
    {
        float h[16];
        float sm = 0.f, sq = 0.f;
        #pragma unroll
        for (int mt4 = 0; mt4 < 4; ++mt4){
            const f32x4 w14 = *(const f32x4*)(W1 + mt4*16 + (q << 2));
            const f32x4 b14 = *(const f32x4*)(b1 + mt4*16 + (q << 2));
            #pragma unroll
            for (int r = 0; r < 4; ++r){
                float v = xv*w14[r] + b14[r];
                h[mt4*4+r] = v; sm += v; sq += v*v;
            }
        }
        sm += __shfl_xor(sm, 16); sm += __shfl_xor(sm, 32);
        sq += __shfl_xor(sq, 16); sq += __shfl_xor(sq, 32);
        const float m   = sm * (1.0f/64.0f);
        const float var = (sq - 64.0f*m*m) * (1.0f/63.0f);
        const float inv = frcp(sqrtf(fmaxf(var, 0.0f)) + EPS);
        #pragma unroll
        for (int mt4 = 0; mt4 < 4; ++mt4){
            const f32x4 g14  = *(const f32x4*)(g1  + mt4*16 + (q << 2));
            const f32x4 be14 = *(const f32x4*)(be1 + mt4*16 + (q << 2));
            #pragma unroll
            for (int r = 0; r < 4; ++r)
                h[mt4*4+r] = ftanh((h[mt4*4+r]-m)*inv*g14[r] + be14[r]);
        }
        #pragma unroll
        for (int mt4 = 0; mt4 < 4; ++mt4){
            int si = ((c16 << 6) + mt4*16 + (q << 2)) ^ swz;
            float a = h[mt4*4+0], b = h[mt4*4+1], c = h[mt4*4+2], d = h[mt4*4+3];
            short4v hi = { bfhi(a), bfhi(b), bfhi(c), bfhi(d) };
            short4v lo = { bfhi(a-bfhif(a)), bfhi(b-bfhif(b)), bfhi(c-bfhif(c)), bfhi(d-bfhif(d)) };
            *(short4v*)(hbw + si)        = hi;
            *(short4v*)(hbw + 1024 + si) = lo;
        }
    }
    __syncthreads();   // wl(L0) staged + hb(input) visible

    f32x4 acc[16];     // gate accumulators; after do_layer, acc[0..3] = h-out

    auto do_layer = [&](LayerParams p, const short* __restrict__ wlofrag, bool writeback){
        bf16x8 bhh[2], bhl[2];
        #pragma unroll
        for (int ks = 0; ks < 2; ++ks){
            int si = ((c16 << 6) + ks*32 + (q << 3)) ^ swz;
            bhh[ks] = *(const bf16x8*)(hbw + si);
            bhl[ks] = *(const bf16x8*)(hbw + 1024 + si);
        }
        #pragma unroll
        for (int mt = 0; mt < 16; ++mt)
            acc[mt] = *(const f32x4*)(p.bi + mt*16 + (q << 2));
        #pragma unroll
        for (int mt = 0; mt < 16; ++mt){
            #pragma unroll
            for (int ks = 0; ks < 2; ++ks){
                int si = ((((mt << 4) + c16) << 6) + ks*32 + (q << 3)) ^ swz;
                bf16x8 whi = *(const bf16x8*)(wl + si);
                bf16x8 wlo = *(const bf16x8*)(wlofrag + ((mt*2 + ks) << 9) + (lane << 3));
                acc[mt] = __builtin_amdgcn_mfma_f32_16x16x32_bf16(whi, bhh[ks], acc[mt], 0, 0, 0);
                acc[mt] = __builtin_amdgcn_mfma_f32_16x16x32_bf16(whi, bhl[ks], acc[mt], 0, 0, 0);
                acc[mt] = __builtin_amdgcn_mfma_f32_16x16x32_bf16(wlo, bhh[ks], acc[mt], 0, 0, 0);
            }
        }
        // LN256 stats
        float sm = 0.f, sq = 0.f;
        #pragma unroll
        for (int mt = 0; mt < 16; ++mt){
            #pragma unroll
            for (int r = 0; r < 4; ++r){ float v = acc[mt][r]; sm += v; sq += v*v; }
        }
        sm += __shfl_xor(sm, 16); sm += __shfl_xor(sm, 32);
        sq += __shfl_xor(sq, 16); sq += __shfl_xor(sq, 32);
        const float m   = sm * (1.0f/256.0f);
        const float var = (sq - 256.0f*m*m) * (1.0f/255.0f);
        const float inv = frcp(sqrtf(fmaxf(var, 0.0f)) + EPS);

        // gates in place: acc[mt4] <- cx = sig(i)*tanh(g); acc[mt4+8] <- o
        #pragma unroll
        for (int mt4 = 0; mt4 < 4; ++mt4){
            const f32x4 giI = *(const f32x4*)(p.gi   +       mt4*16 + (q << 2));
            const f32x4 giO = *(const f32x4*)(p.gi   + 128 + mt4*16 + (q << 2));
            const f32x4 giG = *(const f32x4*)(p.gi   + 192 + mt4*16 + (q << 2));
            const f32x4 adI = *(const f32x4*)(p.addv +       mt4*16 + (q << 2));
            const f32x4 adO = *(const f32x4*)(p.addv + 128 + mt4*16 + (q << 2));
            const f32x4 adG = *(const f32x4*)(p.addv + 192 + mt4*16 + (q << 2));
            #pragma unroll
            for (int r = 0; r < 4; ++r){
                const float i_ = (acc[mt4   ][r]-m)*inv*giI[r] + adI[r];
                const float o_ = (acc[mt4+ 8][r]-m)*inv*giO[r] + adO[r];
                const float g_ = (acc[mt4+12][r]-m)*inv*giG[r] + adG[r];
                acc[mt4   ][r] = fsig(i_) * ftanh(g_);
                acc[mt4+ 8][r] = o_;
            }
        }
        // LN64 over cx (acc[0..3]), then acc[mt4] <- sig(oo)*tanh(LN(cx))
        float s2 = 0.f, q2 = 0.f;
        #pragma unroll
        for (int mt4 = 0; mt4 < 4; ++mt4){
            #pragma unroll
            for (int r = 0; r < 4; ++r){ float v = acc[mt4][r]; s2 += v; q2 += v*v; }
        }
        s2 += __shfl_xor(s2, 16); s2 += __shfl_xor(s2, 32);
        q2 += __shfl_xor(q2, 16); q2 += __shfl_xor(q2, 32);
        const float mc = s2 * (1.0f/64.0f);
        const float vc = (q2 - 64.0f*mc*mc) * (1.0f/63.0f);
        const float ic = frcp(sqrtf(fmaxf(vc, 0.0f)) + EPS);
        #pragma unroll
        for (int mt4 = 0; mt4 < 4; ++mt4){
            const f32x4 gc4 = *(const f32x4*)(p.gc + mt4*16 + (q << 2));
            const f32x4 bc4 = *(const f32x4*)(p.bc + mt4*16 + (q << 2));
            #pragma unroll
            for (int r = 0; r < 4; ++r)
                acc[mt4][r] = fsig(acc[mt4+8][r]) * ftanh((acc[mt4][r]-mc)*ic*gc4[r] + bc4[r]);
        }
        if (writeback){
            #pragma unroll
            for (int mt4 = 0; mt4 < 4; ++mt4){
                int si = ((c16 << 6) + mt4*16 + (q << 2)) ^ swz;
                float a = acc[mt4][0], b = acc[mt4][1], c = acc[mt4][2], d = acc[mt4][3];
                short4v hi = { bfhi(a), bfhi(b), bfhi(c), bfhi(d) };
                short4v lo = { bfhi(a-bfhif(a)), bfhi(b-bfhif(b)), bfhi(c-bfhif(c)), bfhi(d-bfhif(d)) };
                *(short4v*)(hbw + si)        = hi;
                *(short4v*)(hbw + 1024 + si) = lo;
            }
        }
    };

    do_layer({bi0, gi0, ws + 1056, gc0, bc0}, SB,          true);
    __syncthreads();   // all waves done with wl(L0); hb(h1) visible
    stage_hi(Wi1);
    __syncthreads();   // wl(L1) staged
    do_layer({bi1, gi1, ws + 1312, gc1, bc1}, SB + 16384, false);

    // output: out = h2 . Wo + bo  (h2 in acc[0..3])
    float o = 0.f;
    #pragma unroll
    for (int mt4 = 0; mt4 < 4; ++mt4){
        const f32x4 wo4 = *(const f32x4*)(Wo + mt4*16 + (q << 2));
        #pragma unroll
        for (int r = 0; r < 4; ++r) o += acc[mt4][r]*wo4[r];
    }
    o += __shfl_xor(o, 16); o += __shfl_xor(o, 32);
    if (q == 0 && row <= P) out[row] = o + bo[0];
}

// ---------------- fallback: round-3 proven kernel (whi+wlo both in LDS, 96 KB) ----------------
__global__ __launch_bounds__(512, 2) void fwd_lds(
    const float* __restrict__ x,
    const float* __restrict__ W1, const float* __restrict__ b1,
    const float* __restrict__ g1, const float* __restrict__ be1,
    const float* __restrict__ Wi0, const float* __restrict__ bi0,
    const float* __restrict__ gi0, const float* __restrict__ gc0, const float* __restrict__ bc0,
    const float* __restrict__ Wi1, const float* __restrict__ bi1,
    const float* __restrict__ gi1, const float* __restrict__ gc1, const float* __restrict__ bc1,
    const float* __restrict__ Wo, const float* __restrict__ bo,
    const float* __restrict__ ws, float* __restrict__ out, int P)
{
    __shared__ short wl[32768];
    __shared__ short hb[16384];

    const int tid  = threadIdx.x;
    const int wid  = tid >> 6;
    const int lane = tid & 63;
    const int c16  = lane & 15;
    const int q    = lane >> 4;
    const int row  = blockIdx.x*128 + wid*16 + c16;
    short* hbw = hb + wid*2048;
    const int swz = (c16 & 7) << 3;

    auto stage = [&](const float* __restrict__ W){
        #pragma unroll
        for (int i = 0; i < 8; ++i){
            int idx = i*512 + tid;
            int g = idx >> 4, k0 = (idx & 15) << 2;
            f32x4 w4 = *(const f32x4*)(W + (idx << 2));
            int si = ((g << 6) + k0) ^ ((g & 7) << 3);
            short4v hi = { bfhi(w4[0]), bfhi(w4[1]), bfhi(w4[2]), bfhi(w4[3]) };
            short4v lo = { bfhi(w4[0]-bfhif(w4[0])), bfhi(w4[1]-bfhif(w4[1])),
                           bfhi(w4[2]-bfhif(w4[2])), bfhi(w4[3]-bfhif(w4[3])) };
            *(short4v*)(wl + si)         = hi;
            *(short4v*)(wl + 16384 + si) = lo;
        }
    };

    stage(Wi0);

    float xv = 0.0f;
    if (row < P) xv = x[row];
    else if (row == P) xv = ws[0];

    {
        const int cb = q << 4;
        float h[16]; float sm = 0.f, sq = 0.f;
        #pragma unroll
        for (int j = 0; j < 16; ++j){
            float v = xv*W1[cb+j] + b1[cb+j];
            h[j] = v; sm += v; sq += v*v;
        }
        sm += __shfl_xor(sm, 16); sm += __shfl_xor(sm, 32);
        sq += __shfl_xor(sq, 16); sq += __shfl_xor(sq, 32);
        const float m   = sm * (1.0f/64.0f);
        const float var = (sq - 64.0f*m*m) * (1.0f/63.0f);
        const float inv = frcp(sqrtf(fmaxf(var, 0.0f)) + EPS);
        #pragma unroll
        for (int j = 0; j < 16; ++j)
            h[j] = ftanh((h[j]-m)*inv*g1[cb+j] + be1[cb+j]);
        #pragma unroll
        for (int j4 = 0; j4 < 4; ++j4){
            int si = ((c16 << 6) + cb + (j4 << 2)) ^ swz;
            short4v hi = { bfhi(h[j4*4+0]), bfhi(h[j4*4+1]), bfhi(h[j4*4+2]), bfhi(h[j4*4+3]) };
            short4v lo = { bfhi(h[j4*4+0]-bfhif(h[j4*4+0])), bfhi(h[j4*4+1]-bfhif(h[j4*4+1])),
                           bfhi(h[j4*4+2]-bfhif(h[j4*4+2])), bfhi(h[j4*4+3]-bfhif(h[j4*4+3])) };
            *(short4v*)(hbw + si)        = hi;
            *(short4v*)(hbw + 1024 + si) = lo;
        }
    }
    __syncthreads();

    f32x4 acc[16];

    auto do_layer = [&](LayerParams p, bool writeback){
        bf16x8 bhh[2], bhl[2];
        #pragma unroll
        for (int ks = 0; ks < 2; ++ks){
            int si = ((c16 << 6) + ks*32 + (q << 3)) ^ swz;
            bhh[ks] = *(const bf16x8*)(hbw + si);
            bhl[ks] = *(const bf16x8*)(hbw + 1024 + si);
        }
        #pragma unroll
        for (int mt = 0; mt < 16; ++mt)
            acc[mt] = *(const f32x4*)(p.bi + mt*16 + (q << 2));
        #pragma unroll
        for (int mt = 0; mt < 16; ++mt){
            #pragma unroll
            for (int ks = 0; ks < 2; ++ks){
                int si = ((((mt << 4) + c16) << 6) + ks*32 + (q << 3)) ^ swz;
                bf16x8 whi = *(const bf16x8*)(wl + si);
                bf16x8 wlo = *(const bf16x8*)(wl + 16384 + si);
                acc[mt] = __builtin_amdgcn_mfma_f32_16x16x32_bf16(whi, bhh[ks], acc[mt], 0, 0, 0);
                acc[mt] = __builtin_amdgcn_mfma_f32_16x16x32_bf16(whi, bhl[ks], acc[mt], 0, 0, 0);
                acc[mt] = __builtin_amdgcn_mfma_f32_16x16x32_bf16(wlo, bhh[ks], acc[mt], 0, 0, 0);
            }
        }
        float sm = 0.f, sq = 0.f;
        #pragma unroll
        for (int mt = 0; mt < 16; ++mt){
            #pragma unroll
            for (int r = 0; r < 4; ++r){ float v = acc[mt][r]; sm += v; sq += v*v; }
        }
        sm += __shfl_xor(sm, 16); sm += __shfl_xor(sm, 32);
        sq += __shfl_xor(sq, 16); sq += __shfl_xor(sq, 32);
        const float m   = sm * (1.0f/256.0f);
        const float var = (sq - 256.0f*m*m) * (1.0f/255.0f);
        const float inv = frcp(sqrtf(fmaxf(var, 0.0f)) + EPS);

        #pragma unroll
        for (int mt4 = 0; mt4 < 4; ++mt4){
            const f32x4 giI = *(const f32x4*)(p.gi   +       mt4*16 + (q << 2));
            const f32x4 giO = *(const f32x4*)(p.gi   + 128 + mt4*16 + (q << 2));
            const f32x4 giG = *(const f32x4*)(p.gi   + 192 + mt4*16 + (q << 2));
            const f32x4 adI = *(const f32x4*)(p.addv +       mt4*16 + (q << 2));
            const f32x4 adO = *(const f32x4*)(p.addv + 128 + mt4*16 + (q << 2));
            const f32x4 adG = *(const f32x4*)(p.addv + 192 + mt4*16 + (q << 2));
            #pragma unroll
            for (int r = 0; r < 4; ++r){
                const float i_ = (acc[mt4   ][r]-m)*inv*giI[r] + adI[r];
                const float o_ = (acc[mt4+ 8][r]-m)*inv*giO[r] + adO[r];
                const float g_ = (acc[mt4+12][r]-m)*inv*giG[r] + adG[r];
                acc[mt4   ][r] = fsig(i_) * ftanh(g_);
                acc[mt4+ 8][r] = o_;
            }
        }
        float s2 = 0.f, q2 = 0.f;
        #pragma unroll
        for (int mt4 = 0; mt4 < 4; ++mt4){
            #pragma unroll
            for (int r = 0; r < 4; ++r){ float v = acc[mt4][r]; s2 += v; q2 += v*v; }
        }
        s2 += __shfl_xor(s2, 16); s2 += __shfl_xor(s2, 32);
        q2 += __shfl_xor(q2, 16); q2 += __shfl_xor(q2, 32);
        const float mc = s2 * (1.0f/64.0f);
        const float vc = (q2 - 64.0f*mc*mc) * (1.0f/63.0f);
        const float ic = frcp(sqrtf(fmaxf(vc, 0.0f)) + EPS);
        #pragma unroll
        for (int mt4 = 0; mt4 < 4; ++mt4){
            const f32x4 gc4 = *(const f32x4*)(p.gc + mt4*16 + (q << 2));
            const f32x4 bc4 = *(const f32x4*)(p.bc + mt4*16 + (q << 2));
            #pragma unroll
            for (int r = 0; r < 4; ++r)
                acc[mt4][r] = fsig(acc[mt4+8][r]) * ftanh((acc[mt4][r]-mc)*ic*gc4[r] + bc4[r]);
        }
        if (writeback){
            #pragma unroll
            for (int mt4 = 0; mt4 < 4; ++mt4){
                int si = ((c16 << 6) + mt4*16 + (q << 2)) ^ swz;
                float a = acc[mt4][0], b = acc[mt4][1], c = acc[mt4][2], d = acc[mt4][3];
                short4v hi = { bfhi(a), bfhi(b), bfhi(c), bfhi(d) };
                short4v lo = { bfhi(a-bfhif(a)), bfhi(b-bfhif(b)), bfhi(c-bfhif(c)), bfhi(d-bfhif(d)) };
                *(short4v*)(hbw + si)        = hi;
                *(short4v*)(hbw + 1024 + si) = lo;
            }
        }
    };

    do_layer({bi0, gi0, ws + 1056, gc0, bc0}, true);
    __syncthreads();
    stage(Wi1);
    __syncthreads();
    do_layer({bi1, gi1, ws + 1312, gc1, bc1}, false);

    float o = 0.f;
    #pragma unroll
    for (int mt4 = 0; mt4 < 4; ++mt4){
        const f32x4 wo4 = *(const f32x4*)(Wo + mt4*16 + (q << 2));
        #pragma unroll
        for (int r = 0; r < 4; ++r) o += acc[mt4][r]*wo4[r];
    }
    o += __shfl_xor(o, 16); o += __shfl_xor(o, 32);
    if (q == 0 && row <= P) out[row] = o + bo[0];
}

extern "C" void kernel_launch(void* const* d_in, const int* in_sizes, int n_in,
                              void* d_out, int out_size, void* d_ws, size_t ws_size,
                              hipStream_t stream)
{
    (void)n_in; (void)out_size;
    const float* x     = (const float*)d_in[0];
    const float* W1    = (const float*)d_in[1];
    const float* b1    = (const float*)d_in[2];
    const float* g1    = (const float*)d_in[3];
    const float* be1   = (const float*)d_in[4];
    const float* l0_Wi = (const float*)d_in[5];
    const float* l0_bi = (const float*)d_in[6];
    const float* l0_bh = (const float*)d_in[8];
    const float* l0_gi = (const float*)d_in[9];
    const float* l0_bgi= (const float*)d_in[10];
    const float* l0_gh = (const float*)d_in[11];
    const float* l0_bgh= (const float*)d_in[12];
    const float* l0_gc = (const float*)d_in[13];
    const float* l0_bc = (const float*)d_in[14];
    const float* l1_Wi = (const float*)d_in[15];
    const float* l1_bi = (const float*)d_in[16];
    const float* l1_bh = (const float*)d_in[18];
    const float* l1_gi = (const float*)d_in[19];
    const float* l1_bgi= (const float*)d_in[20];
    const float* l1_gh = (const float*)d_in[21];
    const float* l1_bgh= (const float*)d_in[22];
    const float* l1_gc = (const float*)d_in[23];
    const float* l1_bc = (const float*)d_in[24];
    const float* Wo    = (const float*)d_in[25];
    const float* bo    = (const float*)d_in[26];

    int P = in_sizes[0];
    int B = P + 1;
    float* ws  = (float*)d_ws;
    float* out = (float*)d_out;

    mean_part<<<1024, 256, 0, stream>>>(x, P, ws + 16);
    mean_fin<<<1, 1024, 0, stream>>>(ws + 16, ws, P);
    precomp_add<<<2, 256, 0, stream>>>(
        l0_bh, l0_gh, l0_bgh, l0_bgi,
        l1_bh, l1_gh, l1_bgh, l1_bgi, ws);

    if (ws_size >= (size_t)WS_NEED){
        precomp_wlo<<<2, 256, 0, stream>>>(l0_Wi, l1_Wi, ws);
        fwd_stream<<<(B + 63)/64, 256, 0, stream>>>(
            x, W1, b1, g1, be1,
            l0_Wi, l0_bi, l0_gi, l0_gc, l0_bc,
            l1_Wi, l1_bi, l1_gi, l1_gc, l1_bc,
            Wo, bo, ws, out, P);
    } else {
        fwd_lds<<<(B + 127)/128, 512, 0, stream>>>(
            x, W1, b1, g1, be1,
            l0_Wi, l0_bi, l0_gi, l0_gc, l0_bc,
            l1_Wi, l1_bi, l1_gi, l1_gc, l1_bc,
            Wo, bo, ws, out, P);
    }
}